// Round 8
// baseline (12.873 us; speedup 1.0000x reference)
//
#include <hip/hip_runtime.h>
#include <math.h>

#define GRID_G 16
#define K_SLOPE 10.0f
#define LOG2E 1.4426950408889634f
#define GAP2 (4.5f * 4.5f)   // AABB-gap^2 above which IoU <= 4e-6 (proven bound)

__global__ __launch_bounds__(256) void piou_fused_kernel(
    const float* __restrict__ P,   // [N,5] cx,cy,w,h,theta
    const float* __restrict__ T,   // [M,5]
    float* __restrict__ out,       // [N,M]
    int N, int M, int mshift)      // mshift = log2(M) if pow2 else -1
{
    __shared__ int qid[256];          // close-pair id queue (block-compacted)
    __shared__ unsigned int wcnt[4];

    const int tid  = threadIdx.x;
    const int lane = tid & 63;
    const int w    = tid >> 6;
    const int NM   = N * M;

    const float K2    = K_SLOPE * LOG2E;
    const float inv_g = 1.0f / (float)GRID_G;

    // ---- phase 1: lane-parallel classify (1 pair per thread) ----
    int pair = blockIdx.x * 256 + tid;
    bool valid = pair < NM;
    int pc = valid ? pair : 0;
    int i = (mshift >= 0) ? (pc >> mshift) : (pc / M);
    int j = pc - i * M;

    // vectorized box loads: float4 + scalar (dword-aligned dwordx4 is legal)
    float4 bp = *(const float4*)(P + 5*i);
    float  thp = P[5*i+4];
    float4 bt = *(const float4*)(T + 5*j);
    float  tht = T[5*j+4];

    float sp, cp, st, ct;
    __sincosf(thp, &sp, &cp);    // args in [-pi/2,pi/2]; err ~1e-6 -> IoU err << threshold
    __sincosf(tht, &st, &ct);

    float hwp = 0.5f * (bp.z * fabsf(cp) + bp.w * fabsf(sp));
    float hhp = 0.5f * (bp.z * fabsf(sp) + bp.w * fabsf(cp));
    float hwt = 0.5f * (bt.z * fabsf(ct) + bt.w * fabsf(st));
    float hht = 0.5f * (bt.z * fabsf(st) + bt.w * fabsf(ct));

    float gapx = fmaxf(0.f, fabsf(bp.x - bt.x) - (hwp + hwt));
    float gapy = fmaxf(0.f, fabsf(bp.y - bt.y) - (hhp + hht));
    bool close = valid && (gapx * gapx + gapy * gapy <= GAP2);

    if (valid && !close) out[pair] = 0.0f;   // far: IoU <= 4e-6, exact-enough 0

    // ---- block-level compaction (no atomics) ----
    unsigned long long mask = __ballot(close);
    unsigned int myoff = (unsigned int)__popcll(mask & ((1ull << lane) - 1ull));
    if (lane == 0) wcnt[w] = (unsigned int)__popcll(mask);
    __syncthreads();

    unsigned int base = 0;
    #pragma unroll
    for (int u = 0; u < 4; ++u) base += (u < w) ? wcnt[u] : 0u;
    unsigned int C = wcnt[0] + wcnt[1] + wcnt[2] + wcnt[3];

    if (close) qid[base + myoff] = pair;
    __syncthreads();

    // ---- phase 2: heavy path, 16 lanes per pair, 16 pairs per block-iteration ----
    const int g  = tid >> 4;    // group id 0..15
    const int lx = tid & 15;    // lane within group = gx column
    const float fgx = (float)lx;

    for (unsigned int e = g; e < C; e += 16) {
        int bpair = qid[e];
        int bi = (mshift >= 0) ? (bpair >> mshift) : (bpair / M);
        int bj = bpair - bi * M;

        // broadcast reload (16 lanes same address -> single L1 transaction)
        float4 qp = *(const float4*)(P + 5*bi);
        float  qthp = P[5*bi+4];
        float4 qt = *(const float4*)(T + 5*bj);
        float  qtht = T[5*bj+4];

        float sp2, cp2, st2, ct2;
        __sincosf(qthp, &sp2, &cp2);   // identical arithmetic to phase 1
        __sincosf(qtht, &st2, &ct2);

        float qhwp = 0.5f * (qp.z * fabsf(cp2) + qp.w * fabsf(sp2));
        float qhhp = 0.5f * (qp.z * fabsf(sp2) + qp.w * fabsf(cp2));
        float qhwt = 0.5f * (qt.z * fabsf(ct2) + qt.w * fabsf(st2));
        float qhht = 0.5f * (qt.z * fabsf(st2) + qt.w * fabsf(ct2));

        float xmin = fminf(qp.x - qhwp, qt.x - qhwt);
        float xmax = fmaxf(qp.x + qhwp, qt.x + qhwt);
        float ymin = fminf(qp.y - qhhp, qt.y - qhht);
        float ymax = fmaxf(qp.y + qhhp, qt.y + qhht);

        float dxr = xmax - xmin, dyr = ymax - ymin;
        float stepx = dxr * inv_g, stepy = dyr * inv_g;

        float px0 = fmaf(dxr, 0.5f * inv_g, xmin);
        float py0 = fmaf(dyr, 0.5f * inv_g, ymin);
        float dx1 = px0 - qp.x, dy1 = py0 - qp.y;
        float dx2 = px0 - qt.x, dy2 = py0 - qt.y;

        // rotated coords at (gx=0,gy=0) + per-gx / per-gy increments
        float rw1_00 =  dx1*cp2 + dy1*sp2,  iwx1 =  stepx*cp2,  iwy1 = stepy*sp2;
        float rh1_00 = -dx1*sp2 + dy1*cp2,  ihx1 = -stepx*sp2,  ihy1 = stepy*cp2;
        float rw2_00 =  dx2*ct2 + dy2*st2,  iwx2 =  stepx*ct2,  iwy2 = stepy*st2;
        float rh2_00 = -dx2*st2 + dy2*ct2,  ihx2 = -stepx*st2,  ihy2 = stepy*ct2;
        float cwp = -0.5f * K2 * qp.z, chp = -0.5f * K2 * qp.w;
        float cwt = -0.5f * K2 * qt.z, cht = -0.5f * K2 * qt.w;

        // this lane's gx-column base
        float brw1 = fmaf(fgx, iwx1, rw1_00);
        float brh1 = fmaf(fgx, ihx1, rh1_00);
        float brw2 = fmaf(fgx, iwx2, rw2_00);
        float brh2 = fmaf(fgx, ihx2, rh2_00);

        float s1 = 0.f, s2 = 0.f, s12 = 0.f;

        #pragma unroll
        for (int gy = 0; gy < GRID_G; ++gy) {
            float fgy = (float)gy;
            float rw1 = fmaf(fgy, iwy1, brw1);
            float rh1 = fmaf(fgy, ihy1, brh1);
            float rw2 = fmaf(fgy, iwy2, brw2);
            float rh2 = fmaf(fgy, ihy2, brh2);

            float ea1 = __builtin_amdgcn_exp2f(fmaf(K2, fabsf(rw1), cwp));
            float eb1 = __builtin_amdgcn_exp2f(fmaf(K2, fabsf(rh1), chp));
            float ea2 = __builtin_amdgcn_exp2f(fmaf(K2, fabsf(rw2), cwt));
            float eb2 = __builtin_amdgcn_exp2f(fmaf(K2, fabsf(rh2), cht));

            // inf-safe: factors >= 1, rcp(inf)=0 gives exact F=0
            float r1 = __builtin_amdgcn_rcpf((1.0f + ea1) * (1.0f + eb1));
            float r2 = __builtin_amdgcn_rcpf((1.0f + ea2) * (1.0f + eb2));

            s1  += r1;
            s2  += r2;
            s12  = fmaf(r1, r2, s12);
        }

        // 16-lane butterfly (xor masks 1,2,4,8 stay within the aligned group)
        #pragma unroll
        for (int m = 1; m < 16; m <<= 1) {
            s1  += __shfl_xor(s1,  m);
            s2  += __shfl_xor(s2,  m);
            s12 += __shfl_xor(s12, m);
        }

        if (lx == 0)
            out[bpair] = s12 / (s1 + s2 - s12 + 1e-6f);
    }
}

extern "C" void kernel_launch(void* const* d_in, const int* in_sizes, int n_in,
                              void* d_out, int out_size, void* d_ws, size_t ws_size,
                              hipStream_t stream) {
    const float* P = (const float*)d_in[0];
    const float* T = (const float*)d_in[1];
    float* out = (float*)d_out;

    int N = in_sizes[0] / 5;
    int M = in_sizes[1] / 5;
    long long NM = (long long)N * M;

    int mshift = -1;
    if (M > 0 && (M & (M - 1)) == 0) {
        mshift = 0;
        while ((1 << mshift) < M) ++mshift;
    }

    int nblocks = (int)((NM + 255) / 256);   // 256 pairs per block
    piou_fused_kernel<<<nblocks, 256, 0, stream>>>(P, T, out, N, M, mshift);
}